// Round 9
// baseline (67.074 us; speedup 1.0000x reference)
//
#include <hip/hip_runtime.h>
#include <math.h>

#define HW 16384   // 128*128
#define K1CH 64    // channels streamed by kernel1
#define SLICE 7    // weff-hi channels per k1 block: 64*7 = 448

// ws layout (floats):
//   energy  [B*HW]   = 131072
//   part    [B*64]   = 512
//   weffhi  [B*448] float4 (offset 131584 floats, 16B aligned)

// ---------------------------------------------------------------------------
// Kernel 1: attention (R2 mapping) + modulation + stream ch[0,64).
// All pre-work runs BEFORE the stream with no held registers; hiding comes
// from inter-wave overlap (8 waves/CU mix attn-phase and stream-phase).
// ---------------------------------------------------------------------------
__global__ __launch_bounds__(256) void k1(
    const float* __restrict__ input, const float* __restrict__ style,
    const float* __restrict__ a0in, const float* __restrict__ a1in,
    const float* __restrict__ conv_w, const float* __restrict__ mod_w,
    const float* __restrict__ mod_b, const float* __restrict__ q_w,
    const float* __restrict__ q_b, float* __restrict__ energy,
    float* __restrict__ part, float4* __restrict__ weffhi,
    float* __restrict__ outp) {
  __shared__ __align__(16) float st[512];
  __shared__ float4 wl[K1CH];
  __shared__ float qw[27];
  __shared__ float qb_sh;
  __shared__ float partl[4];

  int t = threadIdx.x;
  int blk = blockIdx.x;
  int b = blk >> 6, j = blk & 63;
  int p = j * 256 + t;

  // stage style + query-conv weights
  st[t] = style[b * 512 + t];
  st[t + 256] = style[b * 512 + 256 + t];
  if (t < 27) qw[t] = q_w[t];
  if (t == 27) qb_sh = q_b[0];
  __syncthreads();

  const float kInv = 0.04419417382415922f;  // 1/sqrt(512)

  // ---- weff ch[0,64): 4 threads per channel -> LDS ----
  {
    int c = t >> 2, q = t & 3;
    const float4* row =
        reinterpret_cast<const float4*>(mod_w + (size_t)c * 512) + q * 32;
    const float4* sv = reinterpret_cast<const float4*>(st) + q * 32;
    float s = 0.f;
#pragma unroll
    for (int u = 0; u < 32; ++u) {
      float4 r = row[u];
      float4 sx = sv[u];
      s += r.x * sx.x + r.y * sx.y + r.z * sx.z + r.w * sx.w;
    }
    s += __shfl_xor(s, 1);
    s += __shfl_xor(s, 2);
    if (q == 0) {
      float sm = s * kInv + mod_b[c];
      wl[c] = make_float4(conv_w[c] * kInv * sm, conv_w[512 + c] * kInv * sm,
                          conv_w[1024 + c] * kInv * sm, 0.f);
    }
  }

  // ---- weff slice ch[64+j*7, +7) -> ws ----
  if (t < SLICE * 4) {
    int sI = t >> 2, q = t & 3;
    int c = K1CH + j * SLICE + sI;
    const float4* row =
        reinterpret_cast<const float4*>(mod_w + (size_t)c * 512) + q * 32;
    const float4* sv = reinterpret_cast<const float4*>(st) + q * 32;
    float s = 0.f;
#pragma unroll
    for (int u = 0; u < 32; ++u) {
      float4 r = row[u];
      float4 sx = sv[u];
      s += r.x * sx.x + r.y * sx.y + r.z * sx.z + r.w * sx.w;
    }
    s += __shfl_xor(s, 1);
    s += __shfl_xor(s, 2);
    if (q == 0) {
      float sm = s * kInv + mod_b[c];
      weffhi[(size_t)b * 448 + (c - K1CH)] =
          make_float4(conv_w[c] * kInv * sm, conv_w[512 + c] * kInv * sm,
                      conv_w[1024 + c] * kInv * sm, 0.f);
    }
  }

  // ---- attention energy: R2-exact mapping (cols j*16..j*16+15) ----
  {
    int colLocal = t >> 4;        // 0..15
    int pos = t & 15;             // 0..15
    int col = j * 16 + colLocal;  // 0..1023
    int by = col >> 5, bx = col & 31;
    int iy = pos >> 2, ix = pos & 3;
    int h = by * 4 + iy, w = bx * 4 + ix;

    float pq = qb_sh, pk = qb_sh;
#pragma unroll
    for (int ci = 0; ci < 3; ++ci) {
      const float* p0 = a0in + (size_t)(b * 3 + ci) * HW;
      const float* p1 = a1in + (size_t)(b * 3 + ci) * HW;
#pragma unroll
      for (int ky = 0; ky < 3; ++ky) {
        int hh = h + ky - 1;
        if ((unsigned)hh >= 128u) continue;
#pragma unroll
        for (int kx = 0; kx < 3; ++kx) {
          int ww = w + kx - 1;
          if ((unsigned)ww >= 128u) continue;
          float wq = qw[ci * 9 + ky * 3 + kx];
          pq = fmaf(wq, p0[hh * 128 + ww], pq);
          pk = fmaf(wq, p1[hh * 128 + ww], pk);
        }
      }
    }
    float sq = pq * pq, sk = pk * pk;
#pragma unroll
    for (int m = 1; m < 16; m <<= 1) {
      sq += __shfl_xor(sq, m);
      sk += __shfl_xor(sk, m);
    }
    float qn = 1.0f / fmaxf(sqrtf(sq), 1e-12f);
    float kn = 1.0f / fmaxf(sqrtf(sk), 1e-12f);
    float e = (pq * qn) * (pk * kn);
    energy[(size_t)b * HW + h * 128 + w] = e;

    float ss = e * e;
#pragma unroll
    for (int m = 1; m < 64; m <<= 1) ss += __shfl_xor(ss, m);
    int wid = t >> 6;
    if ((t & 63) == 0) partl[wid] = ss;
  }

  __syncthreads();  // wl + partl ready
  if (t == 0) part[blk] = partl[0] + partl[1] + partl[2] + partl[3];

  // ---- stream ch[0,64) -> partial sums in d_out (R2-style chunks) ----
  const float* in = input + (size_t)b * 512 * HW + p;
  float A0 = 0.f, A1 = 0.f, A2 = 0.f;
  for (int c0 = 0; c0 < K1CH; c0 += 32) {
    float v[32];
#pragma unroll
    for (int u = 0; u < 32; ++u) v[u] = in[(size_t)(c0 + u) * HW];
#pragma unroll
    for (int u = 0; u < 32; ++u) {
      float4 w = wl[c0 + u];
      A0 = fmaf(w.x, v[u], A0);
      A1 = fmaf(w.y, v[u], A1);
      A2 = fmaf(w.z, v[u], A2);
    }
  }
  size_t ob = (size_t)(b * 3) * HW + p;
  outp[ob] = A0;
  outp[ob + HW] = A1;
  outp[ob + 2 * HW] = A2;
}

// ---------------------------------------------------------------------------
// Kernel 2: R2-exact streaming loop over ch[64,512) + partial add + epilogue.
// ---------------------------------------------------------------------------
__global__ __launch_bounds__(256) void k2(
    const float* __restrict__ input, const float4* __restrict__ weffhi,
    const float* __restrict__ bias, const float* __restrict__ skip,
    const float* __restrict__ upk, const float* __restrict__ energy,
    const float* __restrict__ part, float* __restrict__ outp) {
  __shared__ float4 lw[512];  // entries [64,512) used
  __shared__ float ssq_sh;
  int t = threadIdx.x;
  int blk = blockIdx.x;
  int b = blk >> 6, j = blk & 63;
  int p = j * 256 + t;

  // stage weffhi -> lw
  const float4* g = weffhi + (size_t)b * 448;
  if (t < 224) {
    lw[64 + t] = g[t];
    lw[288 + t] = g[224 + t];
  }
  // reduce the 64 per-batch sumsq partials
  if (t < 64) {
    float ps = part[b * 64 + t];
#pragma unroll
    for (int m = 1; m < 64; m <<= 1) ps += __shfl_xor(ps, m);
    if (t == 0) ssq_sh = ps;
  }

  // epilogue inputs, loaded early
  float e = energy[(size_t)b * HW + p];
  size_t ob = (size_t)(b * 3) * HW + p;
  float A0 = outp[ob], A1 = outp[ob + HW], A2 = outp[ob + 2 * HW];
  int y = p >> 7, x = p & 127;
  int syb = ((y + (y & 1)) >> 1) - 1;
  int sxb = ((x + (x & 1)) >> 1) - 1;
  int ky0 = y & 1, kx0 = x & 1;
  float sk0 = 0.f, sk1 = 0.f, sk2 = 0.f;
#pragma unroll
  for (int a = 0; a < 2; ++a) {
    int sy = syb + a;
    if ((unsigned)sy >= 64u) continue;
#pragma unroll
    for (int c2 = 0; c2 < 2; ++c2) {
      int sx = sxb + c2;
      if ((unsigned)sx >= 64u) continue;
      float kv = upk[(ky0 + 2 * a) * 4 + (kx0 + 2 * c2)];
      size_t base = ((size_t)(b * 3) * 64 + sy) * 64 + sx;
      sk0 = fmaf(kv, skip[base], sk0);
      sk1 = fmaf(kv, skip[base + 4096], sk1);
      sk2 = fmaf(kv, skip[base + 8192], sk2);
    }
  }
  float bi0 = bias[0], bi1 = bias[1], bi2 = bias[2];

  __syncthreads();  // lw + ssq_sh ready

  // R2-exact streaming loop, ch 64..511
  const float* in = input + (size_t)b * 512 * HW + p;
  for (int c0 = 64; c0 < 512; c0 += 32) {
    float v[32];
#pragma unroll
    for (int u = 0; u < 32; ++u) v[u] = in[(size_t)(c0 + u) * HW];
#pragma unroll
    for (int u = 0; u < 32; ++u) {
      float4 w = lw[c0 + u];
      A0 = fmaf(w.x, v[u], A0);
      A1 = fmaf(w.y, v[u], A1);
      A2 = fmaf(w.z, v[u], A2);
    }
  }

  float att = e * (4.0f / fmaxf(sqrtf(ssq_sh), 1e-12f));
  float om = 1.0f - att;
  outp[ob] = (A0 + bi0) * att + sk0 * om;
  outp[ob + HW] = (A1 + bi1) * att + sk1 * om;
  outp[ob + 2 * HW] = (A2 + bi2) * att + sk2 * om;
}

// ---------------------------------------------------------------------------
extern "C" void kernel_launch(void* const* d_in, const int* in_sizes, int n_in,
                              void* d_out, int out_size, void* d_ws,
                              size_t ws_size, hipStream_t stream) {
  const float* input  = (const float*)d_in[0];
  const float* style  = (const float*)d_in[1];
  const float* skip   = (const float*)d_in[2];
  const float* att0   = (const float*)d_in[3];
  const float* att1   = (const float*)d_in[4];
  const float* conv_w = (const float*)d_in[5];
  const float* mod_w  = (const float*)d_in[6];
  const float* mod_b  = (const float*)d_in[7];
  const float* bias   = (const float*)d_in[8];
  const float* q_w    = (const float*)d_in[9];
  const float* q_b    = (const float*)d_in[10];
  const float* upk    = (const float*)d_in[11];

  int B = in_sizes[1] / 512;  // 8

  float* ws = (float*)d_ws;
  float* energy = ws;                             // B*HW = 131072
  float* part   = ws + 131072;                    // B*64 = 512
  float4* weffhi = (float4*)(ws + 131072 + 512);  // B*448 float4, 16B aligned
  float* outp = (float*)d_out;

  k1<<<B * 64, 256, 0, stream>>>(input, style, att0, att1, conv_w, mod_w,
                                 mod_b, q_w, q_b, energy, part, weffhi, outp);
  k2<<<B * 64, 256, 0, stream>>>(input, weffhi, bias, skip, upk, energy, part,
                                 outp);
}

// Round 10
// 60.177 us; speedup vs baseline: 1.1146x; 1.1146x over previous
//
#include <hip/hip_runtime.h>
#include <math.h>

#define HW 16384  // 128*128
#define MOD_BLOCKS 64  // lean mod: block m -> channels m*8..m*8+7, all batches

// ---------------------------------------------------------------------------
// Pre-kernel.
//   blocks [0, 64):  modulation, mod_w read ONCE.
//     thread t -> (c_local = t>>5, b = (t&31)>>2, q = t&3); quarter-row dot;
//     reduce over q via shfl; q==0 writes weff4[b*512+c].
//   blocks [64, 64+B*64): attention energy + per-block partial sumsq
//     (R2-exact mapping).
// ---------------------------------------------------------------------------
__global__ __launch_bounds__(256) void pre_kernel(
    const float* __restrict__ style, const float* __restrict__ mod_w,
    const float* __restrict__ mod_b, const float* __restrict__ conv_w,
    const float* __restrict__ a0in, const float* __restrict__ a1in,
    const float* __restrict__ q_w, const float* __restrict__ q_b,
    float4* __restrict__ weff4, float* __restrict__ energy,
    float* __restrict__ part) {
  int bid = blockIdx.x;
  int t = threadIdx.x;
  const float kInv = 0.04419417382415922f;  // 1/sqrt(512)

  if (bid < MOD_BLOCKS) {
    // ---- stage all styles: [8][512] floats = 1024 float4 ----
    __shared__ float4 st4[1024];
    const float4* sg = reinterpret_cast<const float4*>(style);
#pragma unroll
    for (int k = 0; k < 4; ++k) st4[t + k * 256] = sg[t + k * 256];
    __syncthreads();

    int cl = t >> 5;         // 0..7
    int rem = t & 31;
    int b = rem >> 2;        // 0..7
    int q = rem & 3;         // 0..3
    int c = bid * 8 + cl;

    const float4* row = reinterpret_cast<const float4*>(mod_w + (size_t)c * 512)
                        + q * 32;
    const float4* sv = st4 + b * 128 + q * 32;
    float s = 0.f;
#pragma unroll
    for (int u = 0; u < 32; ++u) {
      float4 r = row[u];
      float4 sx = sv[u];
      s += r.x * sx.x + r.y * sx.y + r.z * sx.z + r.w * sx.w;
    }
    s += __shfl_xor(s, 1);
    s += __shfl_xor(s, 2);
    if (q == 0) {
      float sm = s * kInv + mod_b[c];
      weff4[(size_t)b * 512 + c] =
          make_float4(conv_w[c] * kInv * sm, conv_w[512 + c] * kInv * sm,
                      conv_w[1024 + c] * kInv * sm, 0.f);
    }
    return;
  }

  // ---- attention energy (R2-exact) ----
  int blk = bid - MOD_BLOCKS;  // 0 .. B*64-1
  int b = blk >> 6;
  int j = blk & 63;
  int colLocal = t >> 4;        // 0..15
  int pos = t & 15;             // 0..15
  int col = j * 16 + colLocal;  // 0..1023
  int by = col >> 5, bx = col & 31;
  int iy = pos >> 2, ix = pos & 3;
  int h = by * 4 + iy, w = bx * 4 + ix;

  __shared__ float qw[27];
  __shared__ float qb;
  __shared__ float partl[4];
  if (t < 27) qw[t] = q_w[t];
  if (t == 27) qb = q_b[0];
  __syncthreads();

  float pq = qb, pk = qb;
#pragma unroll
  for (int ci = 0; ci < 3; ++ci) {
    const float* p0 = a0in + (size_t)(b * 3 + ci) * HW;
    const float* p1 = a1in + (size_t)(b * 3 + ci) * HW;
#pragma unroll
    for (int ky = 0; ky < 3; ++ky) {
      int hh = h + ky - 1;
      if ((unsigned)hh >= 128u) continue;
#pragma unroll
      for (int kx = 0; kx < 3; ++kx) {
        int ww = w + kx - 1;
        if ((unsigned)ww >= 128u) continue;
        float wq = qw[ci * 9 + ky * 3 + kx];
        pq = fmaf(wq, p0[hh * 128 + ww], pq);
        pk = fmaf(wq, p1[hh * 128 + ww], pk);
      }
    }
  }
  float sq = pq * pq, sk = pk * pk;
#pragma unroll
  for (int m = 1; m < 16; m <<= 1) {
    sq += __shfl_xor(sq, m);
    sk += __shfl_xor(sk, m);
  }
  float qn = 1.0f / fmaxf(sqrtf(sq), 1e-12f);
  float kn = 1.0f / fmaxf(sqrtf(sk), 1e-12f);
  float e = (pq * qn) * (pk * kn);
  energy[(size_t)b * HW + h * 128 + w] = e;

  float ss = e * e;
#pragma unroll
  for (int m = 1; m < 64; m <<= 1) ss += __shfl_xor(ss, m);
  int wid = t >> 6;
  if ((t & 63) == 0) partl[wid] = ss;
  __syncthreads();
  if (t == 0) part[blk] = partl[0] + partl[1] + partl[2] + partl[3];
}

// ---------------------------------------------------------------------------
// Main streaming kernel: R2-exact shape with chunk-0 issued BEFORE the
// prelude (its HBM latency hides under the weff/partials/epilogue loads).
// ---------------------------------------------------------------------------
__global__ __launch_bounds__(256) void main_kernel(
    const float* __restrict__ input, const float4* __restrict__ weff4,
    const float* __restrict__ bias, const float* __restrict__ skip,
    const float* __restrict__ upk, const float* __restrict__ energy,
    const float* __restrict__ part, float* __restrict__ out) {
  __shared__ float4 lw[512];
  __shared__ float ssq_sh;
  int t = threadIdx.x;
  int blk = blockIdx.x;
  int b = blk >> 6;
  int p = (blk & 63) * 256 + t;  // pixel 0..16383

  const float* in = input + (size_t)b * 512 * HW + p;

  // ---- chunk-0 streaming loads first ----
  float va[32];
#pragma unroll
  for (int u = 0; u < 32; ++u) va[u] = in[(size_t)u * HW];

  // ---- stage weff into LDS + reduce this batch's 64 sumsq partials ----
  const float4* g = weff4 + (size_t)b * 512;
  float4 g0 = g[t], g1 = g[t + 256];
  if (t < 64) {
    float ps = part[b * 64 + t];
#pragma unroll
    for (int m = 1; m < 64; m <<= 1) ps += __shfl_xor(ps, m);
    if (t == 0) ssq_sh = ps;
  }
  lw[t] = g0;
  lw[t + 256] = g1;

  // ---- epilogue inputs, loaded early ----
  float e = energy[(size_t)b * HW + p];
  int y = p >> 7, x = p & 127;
  int syb = ((y + (y & 1)) >> 1) - 1;
  int sxb = ((x + (x & 1)) >> 1) - 1;
  int ky0 = y & 1, kx0 = x & 1;
  float s0 = 0.f, s1 = 0.f, s2 = 0.f;
#pragma unroll
  for (int a = 0; a < 2; ++a) {
    int sy = syb + a;
    if ((unsigned)sy >= 64u) continue;
#pragma unroll
    for (int c2 = 0; c2 < 2; ++c2) {
      int sx = sxb + c2;
      if ((unsigned)sx >= 64u) continue;
      float kv = upk[(ky0 + 2 * a) * 4 + (kx0 + 2 * c2)];
      size_t base = ((size_t)(b * 3) * 64 + sy) * 64 + sx;
      s0 = fmaf(kv, skip[base], s0);
      s1 = fmaf(kv, skip[base + 4096], s1);
      s2 = fmaf(kv, skip[base + 8192], s2);
    }
  }
  float bi0 = bias[0], bi1 = bias[1], bi2 = bias[2];

  __syncthreads();  // lw + ssq_sh ready

  // ---- consume chunk 0 ----
  float a0 = 0.f, a1 = 0.f, a2 = 0.f;
#pragma unroll
  for (int u = 0; u < 32; ++u) {
    float4 w = lw[u];
    a0 = fmaf(w.x, va[u], a0);
    a1 = fmaf(w.y, va[u], a1);
    a2 = fmaf(w.z, va[u], a2);
  }

  // ---- chunks 1..15: R2-exact single-buffer loop ----
  for (int c0 = 32; c0 < 512; c0 += 32) {
    float v[32];
#pragma unroll
    for (int u = 0; u < 32; ++u) v[u] = in[(size_t)(c0 + u) * HW];
#pragma unroll
    for (int u = 0; u < 32; ++u) {
      float4 w = lw[c0 + u];
      a0 = fmaf(w.x, v[u], a0);
      a1 = fmaf(w.y, v[u], a1);
      a2 = fmaf(w.z, v[u], a2);
    }
  }

  float att = e * (4.0f / fmaxf(sqrtf(ssq_sh), 1e-12f));
  float om = 1.0f - att;
  size_t ob = (size_t)(b * 3) * HW + p;
  out[ob] = (a0 + bi0) * att + s0 * om;
  out[ob + HW] = (a1 + bi1) * att + s1 * om;
  out[ob + 2 * HW] = (a2 + bi2) * att + s2 * om;
}

// ---------------------------------------------------------------------------
extern "C" void kernel_launch(void* const* d_in, const int* in_sizes, int n_in,
                              void* d_out, int out_size, void* d_ws,
                              size_t ws_size, hipStream_t stream) {
  const float* input  = (const float*)d_in[0];
  const float* style  = (const float*)d_in[1];
  const float* skip   = (const float*)d_in[2];
  const float* att0   = (const float*)d_in[3];
  const float* att1   = (const float*)d_in[4];
  const float* conv_w = (const float*)d_in[5];
  const float* mod_w  = (const float*)d_in[6];
  const float* mod_b  = (const float*)d_in[7];
  const float* bias   = (const float*)d_in[8];
  const float* q_w    = (const float*)d_in[9];
  const float* q_b    = (const float*)d_in[10];
  const float* upk    = (const float*)d_in[11];

  int B = in_sizes[1] / 512;  // 8

  float* ws = (float*)d_ws;
  float4* weff4 = (float4*)ws;          // B*512 float4
  float* energy = ws + 16384;           // B*HW
  float* part   = ws + 16384 + 131072;  // B*64

  pre_kernel<<<MOD_BLOCKS + B * 64, 256, 0, stream>>>(
      style, mod_w, mod_b, conv_w, att0, att1, q_w, q_b, weff4, energy, part);
  main_kernel<<<B * 64, 256, 0, stream>>>(input, weff4, bias, skip, upk,
                                          energy, part, (float*)d_out);
}